// Round 4
// baseline (175.773 us; speedup 1.0000x reference)
//
#include <hip/hip_runtime.h>
#include <hip/hip_bf16.h>

using bf16 = __hip_bfloat16;
typedef short short8 __attribute__((ext_vector_type(8)));
typedef float floatx4 __attribute__((ext_vector_type(4)));

#define NROWS 8192
#define DIM 512
#define ROWB 1024          // DIM * 2 bytes (bf16)
#define BM 256
#define BN 256
#define BK 64
#define NT 8               // DIM / BK

#define AS1(p) ((const __attribute__((address_space(1))) void*)(p))
#define AS3(p) ((__attribute__((address_space(3))) void*)(p))

#if __has_builtin(__builtin_amdgcn_exp2f)
#define EXP2(x) __builtin_amdgcn_exp2f(x)
#else
#define EXP2(x) exp2f(x)
#endif

// ---------------------------------------------------------------------------
// Kernel 1: per-row L2 normalize (fp32 -> bf16), per-row diag dot, zero rowsum
// ---------------------------------------------------------------------------
__global__ __launch_bounds__(256) void prep_kernel(
    const float* __restrict__ v, const float* __restrict__ u,
    bf16* __restrict__ vn, bf16* __restrict__ un,
    float* __restrict__ diag, float* __restrict__ rowsum)
{
    const int row = blockIdx.x;
    const int t = threadIdx.x;
    const float2 a = reinterpret_cast<const float2*>(v + (size_t)row * DIM)[t];
    const float2 b = reinterpret_cast<const float2*>(u + (size_t)row * DIM)[t];
    float sv = a.x * a.x + a.y * a.y;
    float su = b.x * b.x + b.y * b.y;
    float sd = a.x * b.x + a.y * b.y;
#pragma unroll
    for (int m = 32; m; m >>= 1) {
        sv += __shfl_xor(sv, m);
        su += __shfl_xor(su, m);
        sd += __shfl_xor(sd, m);
    }
    __shared__ float red[3][4];
    const int wave = t >> 6;
    if ((t & 63) == 0) { red[0][wave] = sv; red[1][wave] = su; red[2][wave] = sd; }
    __syncthreads();
    sv = red[0][0] + red[0][1] + red[0][2] + red[0][3];
    su = red[1][0] + red[1][1] + red[1][2] + red[1][3];
    sd = red[2][0] + red[2][1] + red[2][2] + red[2][3];
    const float rv = 1.0f / fmaxf(sqrtf(sv), 1e-8f);
    const float ru = 1.0f / fmaxf(sqrtf(su), 1e-8f);
    __hip_bfloat162 ov, ou;
    ov.x = __float2bfloat16(a.x * rv); ov.y = __float2bfloat16(a.y * rv);
    ou.x = __float2bfloat16(b.x * ru); ou.y = __float2bfloat16(b.y * ru);
    reinterpret_cast<__hip_bfloat162*>(vn + (size_t)row * DIM)[t] = ov;
    reinterpret_cast<__hip_bfloat162*>(un + (size_t)row * DIM)[t] = ou;
    if (t == 0) {
        diag[row] = sd * rv * ru;
        rowsum[row] = 0.0f;
    }
}

// ---------------------------------------------------------------------------
// Kernel 2: m201-faithful 256x256 / BK=64 / 8 waves (2Mx4N), 4 phases per
// K-tile, builtin barriers (NO memory clobber -> scheduler may pipeline),
// single counted vmcnt(6) per tile, T2 swizzle, T5 setprio, T1 XCD swizzle.
//
// Half-tiles per K-tile: h0=Alo(rows0-127) h1=Ahi h2=Blo h3=Bhi, 2 gloads ea.
// Per-tile staging order: P0: (t+1).h3->NXT  P1: (t+2).h2->CUR
//                         P2: (t+2).h0->CUR  P3: (t+2).h1->CUR
// WAR safety by schedule: all B reads in P0 (done at P0 lgkmcnt(0), before
// P1's h2 overwrite); all A reads by P1 (before P2/P3's h0/h1 overwrites).
// vmcnt ledger (loads): enter tile t with 6 outstanding {t+1:h3 missing};
// tile stages +8 -> 14; vmcnt(6) at tile end drains t+1's 8 -> tile t+1
// resident; 6 remain = {t+2:h2,h0,h1}. Prologue: t0 all (8), vmcnt(4),
// t1 h0,h1,h2 (6), vmcnt(6). Tile6: vmcnt(0). Tile7: none.
// ---------------------------------------------------------------------------
__global__ __launch_bounds__(512, 2) void simsum_kernel(
    const bf16* __restrict__ A, const bf16* __restrict__ Bm,
    float* __restrict__ rowsum)
{
    __shared__ __align__(16) char lds[131072];   // 2 x (A 32KB + B 32KB)
    const int tid  = threadIdx.x;
    const int wave = tid >> 6;
    const int lane = tid & 63;
    const int ln15 = lane & 15;
    const int lhi  = lane >> 4;
    const int swz  = (lane & 7) << 4;    // read-side XOR key (= row&7)

    // T1: bijective XCD swizzle (1024 blocks, 1024 % 8 == 0)
    const int bid  = blockIdx.x;
    const int wg   = (bid & 7) * 128 + (bid >> 3);
    const int brow = wg >> 5, bcol = wg & 31;

    const int wr = wave >> 2;            // 0..1  -> M half (128 rows)
    const int wc = wave & 3;             // 0..3  -> N quarter (64 cols)

    const char* gA = (const char*)A;
    const char* gB = (const char*)Bm;
    const int growA = brow * BM;
    const int growB = bcol * BN;

    // staging: LDS slot (H*1024 + i*512 + tid)*16 linear; global source
    // column pre-swizzled so the swizzled READ is the inverse (G21).
    const int r0   = tid >> 3;
    const int sl16 = (((tid & 7) ^ ((tid >> 3) & 7)) << 4);

#define STAGEA(BUF, KT, H) do {                                               \
    _Pragma("unroll") for (int i_ = 0; i_ < 2; ++i_) {                        \
        const int row_ = (H) * 128 + i_ * 64 + r0;                            \
        __builtin_amdgcn_global_load_lds(                                     \
            AS1(gA + (size_t)(growA + row_) * ROWB + (KT) * 128 + sl16),      \
            AS3(lds + (BUF) + ((H) * 1024 + i_ * 512 + tid) * 16), 16, 0, 0); \
    } } while (0)

#define STAGEB(BUF, KT, H) do {                                               \
    _Pragma("unroll") for (int i_ = 0; i_ < 2; ++i_) {                        \
        const int row_ = (H) * 128 + i_ * 64 + r0;                            \
        __builtin_amdgcn_global_load_lds(                                     \
            AS1(gB + (size_t)(growB + row_) * ROWB + (KT) * 128 + sl16),      \
            AS3(lds + (BUF) + 32768 +                                         \
                ((H) * 1024 + i_ * 512 + tid) * 16), 16, 0, 0);               \
    } } while (0)

#define RDA(BUF, M, KS)                                                       \
    (*(const short8*)(lds + (BUF) + (wr * 128 + (M) * 16 + ln15) * 128 +      \
                      (((KS) * 64 + lhi * 16) ^ swz)))
#define RDB(BUF, N, KS)                                                       \
    (*(const short8*)(lds + (BUF) + 32768 +                                   \
                      (wc * 64 + (N) * 16 + ln15) * 128 +                     \
                      (((KS) * 64 + lhi * 16) ^ swz)))

#define MFMA16(MB, KS) do {                                                   \
    _Pragma("unroll") for (int mm_ = 0; mm_ < 4; ++mm_)                       \
    _Pragma("unroll") for (int nn_ = 0; nn_ < 4; ++nn_)                       \
        acc[(MB) + mm_][nn_] = __builtin_amdgcn_mfma_f32_16x16x32_bf16(       \
            Af[(MB) + mm_][KS], Bf[nn_][KS], acc[(MB) + mm_][nn_], 0, 0, 0);  \
    } while (0)

// One K-tile, 4 phases. Reads: P0 = B all (8) + A m0-3 (8); P1 = A m4-7 (8).
#define TILE_BODY(CUR, NXT, KT, S1, S2, VMWAIT) do {                          \
    /* ---- P0 ---- */                                                        \
    _Pragma("unroll") for (int n_ = 0; n_ < 4; ++n_)                          \
    _Pragma("unroll") for (int k_ = 0; k_ < 2; ++k_)                          \
        Bf[n_][k_] = RDB(CUR, n_, k_);                                        \
    _Pragma("unroll") for (int m_ = 0; m_ < 4; ++m_)                          \
    _Pragma("unroll") for (int k_ = 0; k_ < 2; ++k_)                          \
        Af[m_][k_] = RDA(CUR, m_, k_);                                        \
    if (S1) STAGEB(NXT, (KT) + 1, 1);                                         \
    asm volatile("s_waitcnt lgkmcnt(8)");                                     \
    __builtin_amdgcn_s_barrier();                                             \
    asm volatile("s_waitcnt lgkmcnt(0)");                                     \
    __builtin_amdgcn_s_setprio(1); MFMA16(0, 0); __builtin_amdgcn_s_setprio(0);\
    __builtin_amdgcn_s_barrier();                                             \
    /* ---- P1 ---- */                                                        \
    _Pragma("unroll") for (int m_ = 0; m_ < 4; ++m_)                          \
    _Pragma("unroll") for (int k_ = 0; k_ < 2; ++k_)                          \
        Af[4 + m_][k_] = RDA(CUR, 4 + m_, k_);                                \
    if (S2) STAGEB(CUR, (KT) + 2, 0);                                         \
    __builtin_amdgcn_s_barrier();                                             \
    asm volatile("s_waitcnt lgkmcnt(0)");                                     \
    __builtin_amdgcn_s_setprio(1); MFMA16(4, 0); __builtin_amdgcn_s_setprio(0);\
    __builtin_amdgcn_s_barrier();                                             \
    /* ---- P2 ---- */                                                        \
    if (S2) STAGEA(CUR, (KT) + 2, 0);                                         \
    __builtin_amdgcn_s_barrier();                                             \
    __builtin_amdgcn_s_setprio(1); MFMA16(0, 1); __builtin_amdgcn_s_setprio(0);\
    __builtin_amdgcn_s_barrier();                                             \
    /* ---- P3 ---- */                                                        \
    if (S2) STAGEA(CUR, (KT) + 2, 1);                                         \
    __builtin_amdgcn_s_barrier();                                             \
    __builtin_amdgcn_s_setprio(1); MFMA16(4, 1); __builtin_amdgcn_s_setprio(0);\
    VMWAIT;                                                                   \
    __builtin_amdgcn_s_barrier();                                             \
    } while (0)

    floatx4 acc[8][4];
#pragma unroll
    for (int m = 0; m < 8; ++m)
#pragma unroll
        for (int n = 0; n < 4; ++n)
            acc[m][n] = (floatx4){0.f, 0.f, 0.f, 0.f};

    short8 Af[8][2], Bf[4][2];

    // ---- prologue: tile0 h0..h3, vmcnt(4); tile1 h0..h2, vmcnt(6) ----
    STAGEA(0, 0, 0);  STAGEA(0, 0, 1);  STAGEB(0, 0, 0);  STAGEB(0, 0, 1);
    asm volatile("s_waitcnt vmcnt(4)");
    STAGEA(65536, 1, 0);  STAGEA(65536, 1, 1);  STAGEB(65536, 1, 0);
    asm volatile("s_waitcnt vmcnt(6)");
    __builtin_amdgcn_s_barrier();

    TILE_BODY(0,     65536, 0, 1, 1, asm volatile("s_waitcnt vmcnt(6)"));
    TILE_BODY(65536, 0,     1, 1, 1, asm volatile("s_waitcnt vmcnt(6)"));
    TILE_BODY(0,     65536, 2, 1, 1, asm volatile("s_waitcnt vmcnt(6)"));
    TILE_BODY(65536, 0,     3, 1, 1, asm volatile("s_waitcnt vmcnt(6)"));
    TILE_BODY(0,     65536, 4, 1, 1, asm volatile("s_waitcnt vmcnt(6)"));
    TILE_BODY(65536, 0,     5, 1, 1, asm volatile("s_waitcnt vmcnt(6)"));
    TILE_BODY(0,     65536, 6, 1, 0, asm volatile("s_waitcnt vmcnt(0)"));
    TILE_BODY(65536, 0,     7, 0, 0, ((void)0));

    // ---- epilogue: rowsum += sum_cols exp(2*sim) via exp2 ----
    // C/D layout: col = lane&15, row = (lane>>4)*4 + reg  [m89/m91 verified]
    const float C2 = 2.885390081777927f;   // 2 * log2(e)
#pragma unroll
    for (int m = 0; m < 8; ++m) {
#pragma unroll
        for (int rr = 0; rr < 4; ++rr) {
            float s = 0.f;
#pragma unroll
            for (int n = 0; n < 4; ++n)
                s += EXP2(acc[m][n][rr] * C2);
            s += __shfl_xor(s, 1);
            s += __shfl_xor(s, 2);
            s += __shfl_xor(s, 4);
            s += __shfl_xor(s, 8);
            if (ln15 == 0) {
                const int grow = growA + wr * 128 + m * 16 + lhi * 4 + rr;
                atomicAdd(&rowsum[grow], s);
            }
        }
    }
}

// ---------------------------------------------------------------------------
// Kernel 3: loss_i = log(exp(2*diag_i) + rowsum_i) - 2*diag_i
// ---------------------------------------------------------------------------
__global__ __launch_bounds__(256) void loss_kernel(
    const float* __restrict__ diag, const float* __restrict__ rowsum,
    float* __restrict__ out)
{
    const int i = blockIdx.x * 256 + threadIdx.x;
    const float d2 = diag[i] * 2.0f;
    out[i] = logf(expf(d2) + rowsum[i]) - d2;
}

extern "C" void kernel_launch(void* const* d_in, const int* in_sizes, int n_in,
                              void* d_out, int out_size, void* d_ws, size_t ws_size,
                              hipStream_t stream) {
    const float* v = (const float*)d_in[0];
    const float* u = (const float*)d_in[1];
    float* out = (float*)d_out;
    char* ws = (char*)d_ws;
    bf16* vn      = (bf16*)ws;                                  // 8 MiB
    bf16* un      = (bf16*)(ws + (size_t)8388608);              // 8 MiB
    float* diag   = (float*)(ws + (size_t)2 * 8388608);         // 32 KiB
    float* rowsum = (float*)(ws + (size_t)2 * 8388608 + 32768); // 32 KiB

    prep_kernel<<<NROWS, 256, 0, stream>>>(v, u, vn, un, diag, rowsum);
    simsum_kernel<<<1024, 512, 0, stream>>>(vn, un, rowsum);
    loss_kernel<<<NROWS / 256, 256, 0, stream>>>(diag, rowsum, out);
}

// Round 5
// 94.209 us; speedup vs baseline: 1.8658x; 1.8658x over previous
//
#include <hip/hip_runtime.h>
#include <hip/hip_bf16.h>

using bf16 = __hip_bfloat16;
typedef short short8 __attribute__((ext_vector_type(8)));
typedef float floatx4 __attribute__((ext_vector_type(4)));

#define NROWS 8192
#define DIM 512
#define ROWB 1024          // DIM * 2 bytes (bf16)
#define NT 8               // DIM / BK, BK = 64

#define AS1(p) ((const __attribute__((address_space(1))) void*)(p))
#define AS3(p) ((__attribute__((address_space(3))) void*)(p))

#if __has_builtin(__builtin_amdgcn_exp2f)
#define EXP2(x) __builtin_amdgcn_exp2f(x)
#else
#define EXP2(x) exp2f(x)
#endif

// ---------------------------------------------------------------------------
// Kernel 1: per-row L2 normalize (fp32 -> bf16), per-row diag dot, zero rowsum
// ---------------------------------------------------------------------------
__global__ __launch_bounds__(256) void prep_kernel(
    const float* __restrict__ v, const float* __restrict__ u,
    bf16* __restrict__ vn, bf16* __restrict__ un,
    float* __restrict__ diag, float* __restrict__ rowsum)
{
    const int row = blockIdx.x;
    const int t = threadIdx.x;
    const float2 a = reinterpret_cast<const float2*>(v + (size_t)row * DIM)[t];
    const float2 b = reinterpret_cast<const float2*>(u + (size_t)row * DIM)[t];
    float sv = a.x * a.x + a.y * a.y;
    float su = b.x * b.x + b.y * b.y;
    float sd = a.x * b.x + a.y * b.y;
#pragma unroll
    for (int m = 32; m; m >>= 1) {
        sv += __shfl_xor(sv, m);
        su += __shfl_xor(su, m);
        sd += __shfl_xor(sd, m);
    }
    __shared__ float red[3][4];
    const int wave = t >> 6;
    if ((t & 63) == 0) { red[0][wave] = sv; red[1][wave] = su; red[2][wave] = sd; }
    __syncthreads();
    sv = red[0][0] + red[0][1] + red[0][2] + red[0][3];
    su = red[1][0] + red[1][1] + red[1][2] + red[1][3];
    sd = red[2][0] + red[2][1] + red[2][2] + red[2][3];
    const float rv = 1.0f / fmaxf(sqrtf(sv), 1e-8f);
    const float ru = 1.0f / fmaxf(sqrtf(su), 1e-8f);
    __hip_bfloat162 ov, ou;
    ov.x = __float2bfloat16(a.x * rv); ov.y = __float2bfloat16(a.y * rv);
    ou.x = __float2bfloat16(b.x * ru); ou.y = __float2bfloat16(b.y * ru);
    reinterpret_cast<__hip_bfloat162*>(vn + (size_t)row * DIM)[t] = ov;
    reinterpret_cast<__hip_bfloat162*>(un + (size_t)row * DIM)[t] = ou;
    if (t == 0) {
        diag[row] = sd * rv * ru;
        rowsum[row] = 0.0f;
    }
}

// ---------------------------------------------------------------------------
// Kernel 2: R1's proven 2-barrier 128x128 structure (multi-block/CU implicit
// overlap), upgraded: BK=64 (128-B LDS rows), XOR-swizzle (0-conflict,
// verified R2-R4), exp2 epilogue. 4 waves, 64x64 per wave, 16 MFMA : 8
// ds_read_b128 per kk-step (m97 hot-loop ratio).
//
// LDS map: A [128][64] bf16 at 0 (16 KB), B at 16384. Row = 128 B.
// Write (gload_lds, linear dest): gload g, thread tid -> LDS byte
//   g*4096 + tid*16  => row r = g*32 + (tid>>3), col chunk c = tid&7,
//   source col chunk pre-swizzled c ^ (r&7)  => LDS[r][c] = G[r][c^(r&7)].
// Read: frag (row rr, chunk cc) at LDS[rr][cc ^ (rr&7)] -> consecutive 8
//   rows hit all 8 chunk slots -> 2-way (free, m136).
// ---------------------------------------------------------------------------
__global__ __launch_bounds__(256, 2) void simsum_kernel(
    const bf16* __restrict__ A, const bf16* __restrict__ Bm,
    float* __restrict__ rowsum)
{
    __shared__ __align__(16) char lds[32768];   // A 16 KB | B 16 KB
    const int tid  = threadIdx.x;
    const int wave = tid >> 6;
    const int lane = tid & 63;
    const int ln15 = lane & 15;
    const int lhi  = lane >> 4;
    const int swz  = (ln15 & 7) << 4;          // read-side XOR (= row&7 <<4)

    const int brow = blockIdx.x, bcol = blockIdx.y;
    const int wr = wave >> 1, wc = wave & 1;   // 2x2 waves, 64x64 each

    const char* gA = (const char*)A;
    const char* gB = (const char*)Bm;
    const int growA = brow * 128;
    const int growB = bcol * 128;

    // staging: gload g covers LDS bytes [g*4096 + tid*16]; source column
    // pre-swizzled so the swizzled read is the inverse (G21).
    const int r0   = tid >> 3;                  // row within 32-row group
    const int sl16 = (((tid & 7) ^ ((tid >> 3) & 7)) << 4);

    floatx4 acc[4][4];
#pragma unroll
    for (int m = 0; m < 4; ++m)
#pragma unroll
        for (int n = 0; n < 4; ++n)
            acc[m][n] = (floatx4){0.f, 0.f, 0.f, 0.f};

    for (int t = 0; t < NT; ++t) {
#pragma unroll
        for (int g = 0; g < 4; ++g) {
            const int row = g * 32 + r0;
            __builtin_amdgcn_global_load_lds(
                AS1(gA + (size_t)(growA + row) * ROWB + t * 128 + sl16),
                AS3(lds + g * 4096 + tid * 16), 16, 0, 0);
        }
#pragma unroll
        for (int g = 0; g < 4; ++g) {
            const int row = g * 32 + r0;
            __builtin_amdgcn_global_load_lds(
                AS1(gB + (size_t)(growB + row) * ROWB + t * 128 + sl16),
                AS3(lds + 16384 + g * 4096 + tid * 16), 16, 0, 0);
        }
        __syncthreads();   // drains vmcnt (staging done) + lgkmcnt

#pragma unroll
        for (int kk = 0; kk < 2; ++kk) {
            short8 Af[4], Bf[4];
#pragma unroll
            for (int m = 0; m < 4; ++m) {
                const int r = wr * 64 + m * 16 + ln15;
                Af[m] = *(const short8*)(lds + r * 128 +
                                         ((kk * 64 + lhi * 16) ^ swz));
            }
#pragma unroll
            for (int n = 0; n < 4; ++n) {
                const int r = wc * 64 + n * 16 + ln15;
                Bf[n] = *(const short8*)(lds + 16384 + r * 128 +
                                         ((kk * 64 + lhi * 16) ^ swz));
            }
#pragma unroll
            for (int m = 0; m < 4; ++m)
#pragma unroll
                for (int n = 0; n < 4; ++n)
                    acc[m][n] = __builtin_amdgcn_mfma_f32_16x16x32_bf16(
                        Af[m], Bf[n], acc[m][n], 0, 0, 0);
        }
        __syncthreads();   // all reads done before next stage overwrites
    }

    // ---- epilogue: rowsum += sum over this block's 128 cols of exp(2*sim)
    // C/D layout: col = lane&15, row = (lane>>4)*4 + reg  [m89/m91 verified]
    const float C2 = 2.885390081777927f;   // 2 * log2(e)
#pragma unroll
    for (int m = 0; m < 4; ++m) {
#pragma unroll
        for (int rr = 0; rr < 4; ++rr) {
            float s = 0.f;
#pragma unroll
            for (int n = 0; n < 4; ++n)
                s += EXP2(acc[m][n][rr] * C2);
            s += __shfl_xor(s, 1);
            s += __shfl_xor(s, 2);
            s += __shfl_xor(s, 4);
            s += __shfl_xor(s, 8);
            if (ln15 == 0) {
                const int grow = growA + wr * 64 + m * 16 + lhi * 4 + rr;
                atomicAdd(&rowsum[grow], s);
            }
        }
    }
}

// ---------------------------------------------------------------------------
// Kernel 3: loss_i = log(exp(2*diag_i) + rowsum_i) - 2*diag_i
// ---------------------------------------------------------------------------
__global__ __launch_bounds__(256) void loss_kernel(
    const float* __restrict__ diag, const float* __restrict__ rowsum,
    float* __restrict__ out)
{
    const int i = blockIdx.x * 256 + threadIdx.x;
    const float d2 = diag[i] * 2.0f;
    out[i] = logf(expf(d2) + rowsum[i]) - d2;
}

extern "C" void kernel_launch(void* const* d_in, const int* in_sizes, int n_in,
                              void* d_out, int out_size, void* d_ws, size_t ws_size,
                              hipStream_t stream) {
    const float* v = (const float*)d_in[0];
    const float* u = (const float*)d_in[1];
    float* out = (float*)d_out;
    char* ws = (char*)d_ws;
    bf16* vn      = (bf16*)ws;                                  // 8 MiB
    bf16* un      = (bf16*)(ws + (size_t)8388608);              // 8 MiB
    float* diag   = (float*)(ws + (size_t)2 * 8388608);         // 32 KiB
    float* rowsum = (float*)(ws + (size_t)2 * 8388608 + 32768); // 32 KiB

    prep_kernel<<<NROWS, 256, 0, stream>>>(v, u, vn, un, diag, rowsum);
    dim3 grid(64, 64);
    simsum_kernel<<<grid, 256, 0, stream>>>(vn, un, rowsum);
    loss_kernel<<<NROWS / 256, 256, 0, stream>>>(diag, rowsum, out);
}